// Round 10
// baseline (390.766 us; speedup 1.0000x reference)
//
#include <hip/hip_runtime.h>
#include <stdint.h>

// ---------------------------------------------------------------------------
// EdgeNodeGCN on MI355X (gfx950). Inputs fp32, edge_index int32, output fp32.
// Factorization:
//   P[n]  = x[n] @ (Wa - Wb) + b_edge   (Wa = W_edge[0:128], Wb = W_edge[128:256])
//   Q[n]  = x[n] @ Wb
//   msg(e)= relu(P[dst] + Q[src]);  edge_agg[d] = sum msg
//   XA[d] = sum_{e->d} x[src]           (segment_sum commutes with @W_node)
//   nodes = relu(XA @ W_node + b_node); edges = relu(edge_agg @ W_ed + b_ed)
//   out   = sigmoid(relu([nodes|edges] @ W_f1 + b_f1) @ W_f2 + b_f2)
//
// R19 vs R18 (281 us): R18's a[8][4] batching was DEFEATED by the compiler
// (VGPR_Count=32, loads re-sunk, dur 63 unchanged) + stride-136 added 200K
// bank conflicts. Two nulls on k_gemm -> stop fighting the scheduler.
// Budget: cs~60 + gemm 63 + gather~60 + tail~15, ALL latency-bound with idle
// pipes. Lever = OVERLAP: R13 showed scatter+gemm co-resident = 75 vs 63
// pure (scatter ~12us marginal). Break the convert->gemm dependency: gemm
// reads x fp32 DIRECTLY with inline f2bf (bit-identical to via-xb path).
// One fused dispatch, roles b%4: {0,1}=gemm, 2=scatter, 3=conv(x->xb for
// gather). Tiny k_w transposes weights first (~5us). LDS stride back to 132
// (0 conflicts), simple per-tile loads.
// Predicted: k_fused 75-95us (vs 123 serial), total 281 -> ~200-215.
// Dispatches: memset x2, k_w, k_fused, gather, tail.
// ---------------------------------------------------------------------------

typedef short short8 __attribute__((ext_vector_type(8)));
typedef float f32x4 __attribute__((ext_vector_type(4)));
typedef float float4v __attribute__((ext_vector_type(4)));
typedef unsigned short us8 __attribute__((ext_vector_type(8)));
typedef unsigned short us4 __attribute__((ext_vector_type(4)));

__device__ inline float bf2f(unsigned short h) {
    union { unsigned int u; float f; } v;
    v.u = ((unsigned int)h) << 16;
    return v.f;
}
__device__ inline unsigned short f2bf(float f) {
    union { float f; unsigned int u; } v;
    v.f = f;
    unsigned int r = v.u + 0x7FFFu + ((v.u >> 16) & 1u);  // RNE
    return (unsigned short)(r >> 16);
}

// ---- weights -> bf16 transposes (coalesced writes), 560x256 = 143360 ------
__global__ __launch_bounds__(256) void k_w(
    const float* __restrict__ W_edge, const float* __restrict__ W_node,
    const float* __restrict__ W_ed, const float* __restrict__ W_f1,
    unsigned short* __restrict__ WE2T, unsigned short* __restrict__ WnT,
    unsigned short* __restrict__ WdT, unsigned short* __restrict__ Wf1P)
{
    int j = blockIdx.x * 256 + threadIdx.x;
    if (j < 65536) {                          // WE2T [512 c][128 k]
        int c = j >> 7, k = j & 127;
        float v;
        if (c < 256) v = W_edge[k * 256 + c] - W_edge[(k + 128) * 256 + c];
        else         v = W_edge[(k + 128) * 256 + (c - 256)];
        WE2T[j] = f2bf(v);
    } else if (j < 65536 + 32768) {           // WnT [256 c][128 k]
        int t = j - 65536;
        int c = t >> 7, k = t & 127;
        WnT[t] = f2bf(W_node[k * 256 + c]);
    } else if (j < 65536 + 65536) {           // WdT [128 c][256 k]
        int t = j - 65536 - 32768;
        int c = t >> 8, k = t & 255;
        WdT[t] = f2bf(W_ed[k * 128 + c]);
    } else if (j < 143360) {                  // Wf1P [32 c][384 kp] permuted
        int t = j - 65536 - 65536;
        int c = t / 384, kp = t - c * 384;
        int w = kp / 96, idx = kp % 96;
        int korig;
        if (idx < 64) korig = (w + (idx >> 4) * 4) * 16 + (idx & 15);
        else          korig = 256 + (w + ((idx - 64) >> 4) * 4) * 16 + (idx & 15);
        Wf1P[t] = f2bf(W_f1[korig * 32 + c]);
    }
}

// ---- fused: GEMM1(from x, inline f2bf) + scatter + xb-convert -------------
// Roles by b%4: 0,1 -> gemm (g=(b>>2)*2+(b&3)); 2 -> scatter; 3 -> conv.
__global__ __launch_bounds__(512) void k_fused(
    const float* __restrict__ x,               // [N][128] fp32
    const unsigned short* __restrict__ WE2T,   // [512][128] bf16 col-major
    const float* __restrict__ b_edge,          // [256] fp32
    const int* __restrict__ src, const int* __restrict__ dst,
    unsigned short* __restrict__ xb,           // [N][128] bf16 (for gather)
    unsigned short* __restrict__ T,            // [N][512]
    int* __restrict__ head, int* __restrict__ deg, int* __restrict__ adj,
    unsigned long long* __restrict__ next2,
    int quads, int N, int E, int row_tiles, int gemm_blocks)
{
    __shared__ unsigned short st[8][16 * 132];
    int b = blockIdx.x;
    int role = b & 3;

    if (role == 2) {                           // ---- scatter: padded CSR ----
        int sid = b >> 2;
        int i = sid * 512 + threadIdx.x;
        if (i >= E) return;
        int s = src[i], d = dst[i];
        if ((unsigned)d >= (unsigned)N || (unsigned)s >= (unsigned)N) return;
        int pos = atomicAdd(&deg[d], 1);
        if (pos < 32) {
            adj[(size_t)d * 32 + pos] = s;
        } else {                               // overflow: linked list
            int old = atomicExch(&head[d], i);
            next2[i] = ((unsigned long long)(unsigned)s << 32) | (unsigned)old;
        }
        return;
    }
    if (role == 3) {                           // ---- conv: x -> xb ----
        int cid = b >> 2;
        int tid = threadIdx.x;
#pragma unroll
        for (int k = 0; k < 4; ++k) {
            int i = cid * 2048 + k * 512 + tid;
            if (i < quads) {
                float4v v = ((const float4v*)x)[i];
                us4 o;
                for (int j = 0; j < 4; ++j) o[j] = f2bf(v[j]);
                ((us4*)xb)[i] = o;
            }
        }
        return;
    }

    // ---- gemm role ----
    int g = (b >> 2) * 2 + role;               // role 0/1
    if (g >= gemm_blocks) return;
    int gx = g >> 2;                           // row group (8 tiles)
    int gy = g & 3;                            // col quarter (128 cols)

    const int lane = threadIdx.x & 63;
    const int wave = threadIdx.x >> 6;
    const int quad = lane >> 4;
    const int col16 = lane & 15;
    const int lcol = wave * 16 + col16;        // 0..127
    const int col = gy * 128 + lcol;           // 0..511

    float bias = (col < 256) ? b_edge[col] : 0.f;

    short8 bf[4];
#pragma unroll
    for (int ks = 0; ks < 4; ++ks)
        bf[ks] = *(const short8*)(WE2T + (size_t)col * 128 + ks * 32 + quad * 8);

    const int tid = threadIdx.x;
    const int srow = tid >> 5;                 // 0..15
    const int sc4 = (tid & 31) * 4;            // 0..124
    const int tbase = gx * 8;

    int tmax = row_tiles - tbase;
    if (tmax > 8) tmax = 8;

    for (int t = 0; t < 8; ++t) {
        if (t >= tmax) break;
        int r0 = (tbase + t) * 16;
        int arow = r0 + col16;
        if (arow >= N) arow = N - 1;
        f32x4 acc = {0.f, 0.f, 0.f, 0.f};
        const float* ap = x + (size_t)arow * 128 + quad * 8;
#pragma unroll
        for (int ks = 0; ks < 4; ++ks) {
            float4v f0 = *(const float4v*)(ap + ks * 32);
            float4v f1 = *(const float4v*)(ap + ks * 32 + 4);
            short8 a;
            for (int j = 0; j < 4; ++j) {
                a[j] = (short)f2bf(f0[j]);
                a[j + 4] = (short)f2bf(f1[j]);
            }
            acc = __builtin_amdgcn_mfma_f32_16x16x32_bf16(a, bf[ks], acc, 0, 0, 0);
        }
        unsigned short* sbuf = st[t];
        for (int r = 0; r < 4; ++r)
            sbuf[(quad * 4 + r) * 132 + lcol] = f2bf(acc[r] + bias);
    }

    __syncthreads();                           // one barrier per block

    for (int t = 0; t < 8; ++t) {
        if (t >= tmax) break;
        int r0 = (tbase + t) * 16;
        if (r0 + srow >= N) continue;
        us4 v = *(const us4*)(st[t] + srow * 132 + sc4);
        *(us4*)(T + (size_t)(r0 + srow) * 512 + gy * 128 + sc4) = v;
    }
}

// ---- Gather: half-wave per node over padded-CSR adjacency -----------------
__global__ __launch_bounds__(256) void k_gather(
    unsigned short* __restrict__ T,          // [N][512]: P|Q -> EA over P
    const unsigned short* __restrict__ xb,   // [N][128]
    unsigned short* __restrict__ XA,         // [N][128]
    const int* __restrict__ deg,
    const int* __restrict__ adj,             // [N][32]
    const int* __restrict__ head,
    const unsigned long long* __restrict__ next2, int N)
{
    int wave = threadIdx.x >> 6;
    int lane = threadIdx.x & 63;
    int half = lane >> 5;
    int c = lane & 31;
    int n = blockIdx.x * 8 + wave * 2 + half;
    bool act = n < N;
    int nn = act ? n : N - 1;
    int c8 = c * 8, c4 = c * 4;

    us8 pv = *(const us8*)(T + (size_t)nn * 512 + c8);
    float p[8];
    for (int j = 0; j < 8; ++j) p[j] = bf2f(pv[j]);
    float aE[8] = {0, 0, 0, 0, 0, 0, 0, 0};
    float aX[4] = {0, 0, 0, 0};

    int dg = act ? deg[n] : 0;                 // uniform within half-wave
    int adjv = adj[(size_t)nn * 32 + c];       // one coalesced 4B/lane read
    int m = dg < 32 ? dg : 32;

    int k = 0;
    for (; k + 1 < m; k += 2) {                // 2-way unroll: independent loads
        int s0 = __shfl(adjv, k, 32);
        int s1 = __shfl(adjv, k + 1, 32);
        us8 q0 = *(const us8*)(T + (size_t)s0 * 512 + 256 + c8);
        us8 q1 = *(const us8*)(T + (size_t)s1 * 512 + 256 + c8);
        us4 x0 = *(const us4*)(xb + (size_t)s0 * 128 + c4);
        us4 x1 = *(const us4*)(xb + (size_t)s1 * 128 + c4);
        for (int j = 0; j < 8; ++j) {
            aE[j] += fmaxf(p[j] + bf2f(q0[j]), 0.f);
            aE[j] += fmaxf(p[j] + bf2f(q1[j]), 0.f);
        }
        for (int j = 0; j < 4; ++j)
            aX[j] += bf2f(x0[j]) + bf2f(x1[j]);
    }
    if (k < m) {
        int s0 = __shfl(adjv, k, 32);
        us8 q0 = *(const us8*)(T + (size_t)s0 * 512 + 256 + c8);
        us4 x0 = *(const us4*)(xb + (size_t)s0 * 128 + c4);
        for (int j = 0; j < 8; ++j) aE[j] += fmaxf(p[j] + bf2f(q0[j]), 0.f);
        for (int j = 0; j < 4; ++j) aX[j] += bf2f(x0[j]);
    }

    // Overflow fallback (deg > 32): walk residual linked list.
    int cur = (act && dg > 32) ? head[n] : -1;
    while (__any(cur >= 0)) {
        bool v = cur >= 0;
        int safe = v ? cur : 0;
        unsigned long long e2 = next2[safe];
        int s = (int)(e2 >> 32);
        float mm = v ? 1.f : 0.f;
        const unsigned short* tb = T + (size_t)s * 512;
        us8 qv = *(const us8*)(tb + 256 + c8);
        us4 xv = *(const us4*)(xb + (size_t)s * 128 + c4);
        for (int j = 0; j < 8; ++j)
            aE[j] += mm * fmaxf(p[j] + bf2f(qv[j]), 0.f);
        for (int j = 0; j < 4; ++j)
            aX[j] += mm * bf2f(xv[j]);
        cur = v ? (int)(unsigned)(e2 & 0xFFFFFFFFull) : -1;
    }

    if (act) {
        us8 ev;
        for (int j = 0; j < 8; ++j) ev[j] = f2bf(aE[j]);
        *(us8*)(T + (size_t)n * 512 + c8) = ev;       // EA over own P slot: safe
        us4 xo;
        for (int j = 0; j < 4; ++j) xo[j] = f2bf(aX[j]);
        *(us4*)(XA + (size_t)n * 128 + c4) = xo;
    }
}

// ---- Fused tail: persistent-weight multi-tile blocks ----------------------
__global__ __launch_bounds__(256, 2) void k_tail(
    const unsigned short* __restrict__ T,    // EA in cols 0-255
    const unsigned short* __restrict__ XA,   // [N][128]
    const unsigned short* __restrict__ WnT,  // [256 c][128 k] col-major
    const unsigned short* __restrict__ WdT,  // [128 c][256 k] col-major
    const unsigned short* __restrict__ Wf1P, // [32 c][384 kp] permuted
    const float* __restrict__ b_node, const float* __restrict__ b_ed,
    const float* __restrict__ b_f1, const float* __restrict__ W_f2,
    const float* __restrict__ b_f2,
    float* __restrict__ out, int N, int row_tiles, int tiles_per_block)
{
    __shared__ unsigned short hslice[4][16 * 100];  // per-wave h (bf16), pad 100
    __shared__ float red[4][16][33];                // MLP partials, pad 33
    const int wave = threadIdx.x >> 6;
    const int lane = threadIdx.x & 63;
    const int quad = lane >> 4;
    const int col16 = lane & 15;

    // ---- persistent B fragments (loaded once per block) ----
    short8 bn[4][4], be[2][8], bfr[2][3];
    float bias_n[4], bias_e[2];
#pragma unroll
    for (int ci = 0; ci < 4; ++ci) {
        int col = (wave + ci * 4) * 16 + col16;
        bias_n[ci] = b_node[col];
#pragma unroll
        for (int ks = 0; ks < 4; ++ks)
            bn[ci][ks] = *(const short8*)(WnT + (size_t)col * 128 + ks * 32 + quad * 8);
    }
#pragma unroll
    for (int ci = 0; ci < 2; ++ci) {
        int col = (wave + ci * 4) * 16 + col16;
        bias_e[ci] = b_ed[col];
#pragma unroll
        for (int ks = 0; ks < 8; ++ks)
            be[ci][ks] = *(const short8*)(WdT + (size_t)col * 256 + ks * 32 + quad * 8);
    }
#pragma unroll
    for (int cc = 0; cc < 2; ++cc) {
        int c = cc * 16 + col16;
#pragma unroll
        for (int ks = 0; ks < 3; ++ks)
            bfr[cc][ks] = *(const short8*)(Wf1P + (size_t)c * 384 + wave * 96 + ks * 32 + quad * 8);
    }

    unsigned short* hw = &hslice[wave][0];
    int t0 = blockIdx.x * tiles_per_block;
    int t1 = t0 + tiles_per_block;
    if (t1 > row_tiles) t1 = row_tiles;

    for (int tile = t0; tile < t1; ++tile) {
        int r0 = tile * 16;
        int arow = r0 + col16;
        if (arow >= N) arow = N - 1;

        // --- node path: h[:,0:256], this wave's 4 chunks ---
        short8 ax[4];
        {
            const unsigned short* xap = XA + (size_t)arow * 128 + quad * 8;
#pragma unroll
            for (int ks = 0; ks < 4; ++ks) ax[ks] = *(const short8*)(xap + ks * 32);
        }
#pragma unroll
        for (int ci = 0; ci < 4; ++ci) {
            f32x4 acc = {0.f, 0.f, 0.f, 0.f};
#pragma unroll
            for (int ks = 0; ks < 4; ++ks)
                acc = __builtin_amdgcn_mfma_f32_16x16x32_bf16(ax[ks], bn[ci][ks], acc, 0, 0, 0);
#pragma unroll
            for (int r = 0; r < 4; ++r)
                hw[(quad * 4 + r) * 100 + ci * 16 + col16] =
                    f2bf(fmaxf(acc[r] + bias_n[ci], 0.f));
        }

        // --- edge path: h[:,256:384], this wave's 2 chunks ---
        short8 ae[8];
        {
            const unsigned short* eap = T + (size_t)arow * 512 + quad * 8;
#pragma unroll
            for (int ks = 0; ks < 8; ++ks) ae[ks] = *(const short8*)(eap + ks * 32);
        }
#pragma unroll
        for (int ci = 0; ci < 2; ++ci) {
            f32x4 acc = {0.f, 0.f, 0.f, 0.f};
#pragma unroll
            for (int ks = 0; ks < 8; ++ks)
                acc = __builtin_amdgcn_mfma_f32_16x16x32_bf16(ae[ks], be[ci][ks], acc, 0, 0, 0);
#pragma unroll
            for (int r = 0; r < 4; ++r)
                hw[(quad * 4 + r) * 100 + 64 + ci * 16 + col16] =
                    f2bf(fmaxf(acc[r] + bias_e[ci], 0.f));
        }

        // --- MLP partial over own 96-K slice (same-wave LDS, no barrier) ---
        f32x4 m0 = {0.f, 0.f, 0.f, 0.f}, m1 = {0.f, 0.f, 0.f, 0.f};
#pragma unroll
        for (int ks = 0; ks < 3; ++ks) {
            short8 a = *(const short8*)(hw + col16 * 100 + ks * 32 + quad * 8);
            m0 = __builtin_amdgcn_mfma_f32_16x16x32_bf16(a, bfr[0][ks], m0, 0, 0, 0);
            m1 = __builtin_amdgcn_mfma_f32_16x16x32_bf16(a, bfr[1][ks], m1, 0, 0, 0);
        }
#pragma unroll
        for (int r = 0; r < 4; ++r) {
            red[wave][quad * 4 + r][col16] = m0[r];
            red[wave][quad * 4 + r][16 + col16] = m1[r];
        }
        __syncthreads();

        // --- final reduce + MLP2 + sigmoid on wave 0 ---
        if (wave == 0) {
            int row = col16, g = quad;          // each lane: 8 cols of one row
            float s = 0.f;
#pragma unroll
            for (int cc = 0; cc < 8; ++cc) {
                int col = g * 8 + cc;
                float v = red[0][row][col] + red[1][row][col] +
                          red[2][row][col] + red[3][row][col] + b_f1[col];
                s += fmaxf(v, 0.f) * W_f2[col];
            }
            s += __shfl_xor(s, 16, 64);
            s += __shfl_xor(s, 32, 64);
            if (g == 0 && r0 + row < N) {
                float v = s + b_f2[0];
                out[r0 + row] = 1.f / (1.f + __expf(-v));
            }
        }
        __syncthreads();   // red reused next tile
    }
}

extern "C" void kernel_launch(void* const* d_in, const int* in_sizes, int n_in,
                              void* d_out, int out_size, void* d_ws, size_t ws_size,
                              hipStream_t stream) {
    const float* x      = (const float*)d_in[0];
    const int*   ei     = (const int*)d_in[1];
    // d_in[2] = e (unused)
    const float* W_node = (const float*)d_in[3];
    const float* b_node = (const float*)d_in[4];
    const float* W_edge = (const float*)d_in[5];
    const float* b_edge = (const float*)d_in[6];
    const float* W_ed   = (const float*)d_in[7];
    const float* b_ed   = (const float*)d_in[8];
    const float* W_f1   = (const float*)d_in[9];
    const float* b_f1   = (const float*)d_in[10];
    const float* W_f2   = (const float*)d_in[11];
    const float* b_f2   = (const float*)d_in[12];

    const int N = in_sizes[0] / 128;
    const int E = in_sizes[1] / 2;
    const int* src = ei;
    const int* dst = ei + E;

    char* ws = (char*)d_ws;
    size_t off = 0;
    auto alloc = [&](size_t bytes) { size_t o = off; off += (bytes + 255) & ~(size_t)255; return o; };
    unsigned short* xb   = (unsigned short*)(ws + alloc((size_t)N * 128 * 2));
    unsigned short* WE2T = (unsigned short*)(ws + alloc(512 * 128 * 2));
    unsigned short* WnT  = (unsigned short*)(ws + alloc(256 * 128 * 2));
    unsigned short* WdT  = (unsigned short*)(ws + alloc(128 * 256 * 2));
    unsigned short* Wf1P = (unsigned short*)(ws + alloc(32 * 384 * 2));
    unsigned short* T    = (unsigned short*)(ws + alloc((size_t)N * 512 * 2));
    unsigned short* XA   = (unsigned short*)(ws + alloc((size_t)N * 128 * 2));
    int* head            = (int*)(ws + alloc((size_t)N * 4));
    unsigned long long* next2 = (unsigned long long*)(ws + alloc((size_t)E * 8));
    int* deg             = (int*)(ws + alloc((size_t)N * 4));
    int* adj             = (int*)(ws + alloc((size_t)N * 32 * 4));

    const int row_tiles   = (N + 15) / 16;
    const int row_groups  = (row_tiles + 7) / 8;
    const int quads       = N * 128 / 4;
    const int gemm_blocks = row_groups * 4;

    // role-slot count: max over {gemm needs ceil(gemm_blocks/2), scatter
    // needs ceil(E/512), conv needs ceil(quads/2048)}
    int m = (gemm_blocks + 1) / 2;
    int sneed = (E + 511) / 512;
    if (sneed > m) m = sneed;
    int cneed = (quads + 2047) / 2048;
    if (cneed > m) m = cneed;
    const int grid_fused = 4 * m;

    // init happens-before scatter via stream order
    hipMemsetAsync(head, 0xFF, (size_t)N * 4, stream);   // -1
    hipMemsetAsync(deg, 0x00, (size_t)N * 4, stream);

    k_w<<<560, 256, 0, stream>>>(W_edge, W_node, W_ed, W_f1,
                                 WE2T, WnT, WdT, Wf1P);
    k_fused<<<grid_fused, 512, 0, stream>>>(
        x, WE2T, b_edge, src, dst, xb, T, head, deg, adj, next2,
        quads, N, E, row_tiles, gemm_blocks);
    k_gather<<<(N + 7) / 8, 256, 0, stream>>>(T, xb, XA, deg, adj, head, next2, N);

    int tail_blocks = 512;
    if (tail_blocks > row_tiles) tail_blocks = row_tiles;
    int tpb = (row_tiles + tail_blocks - 1) / tail_blocks;
    k_tail<<<tail_blocks, 256, 0, stream>>>(
        T, XA, WnT, WdT, Wf1P, b_node, b_ed, b_f1, W_f2, b_f2,
        (float*)d_out, N, row_tiles, tpb);
}

// Round 12
// 233.067 us; speedup vs baseline: 1.6766x; 1.6766x over previous
//
#include <hip/hip_runtime.h>
#include <stdint.h>

// ---------------------------------------------------------------------------
// EdgeNodeGCN on MI355X (gfx950). Inputs fp32, edge_index int32, output fp32.
// Factorization:
//   P[n]  = x[n] @ (Wa - Wb) + b_edge   (Wa = W_edge[0:128], Wb = W_edge[128:256])
//   Q[n]  = x[n] @ Wb
//   msg(e)= relu(P[dst] + Q[src]);  edge_agg[d] = sum msg
//   XA[d] = sum_{e->d} x[src]           (segment_sum commutes with @W_node)
//   nodes = relu(XA @ W_node + b_node); edges = relu(edge_agg @ W_ed + b_ed)
//   out   = sigmoid(relu([nodes|edges] @ W_f1 + b_f1) @ W_f2 + b_f2)
//
// R21 == R20 resubmit (R20 never ran: GPU acquisition timeout).
// R20: R19 regressed 281->391 (k_fused 208us: direct-fp32 x read 4x = FETCH
// 25->66MB, inline f2bf serialized into MFMA chain). REVERT to best-measured
// R13 (262us) + ONE structural change to its gemm: WIDE BLOCKS. One block
// per 8-tile row group, 8 waves x 64 cols each (bf[4][4] persistent, 64
// VGPR). Same 4 A-loads/wave/tile now feed 16 MFMAs (4x intensity - the
// compiler can't re-sink this, unlike R18) and xb is read ONCE not 4x
// (gemm A-traffic 51->12.8MB). Double-buffered LDS [2][16*524], one barrier
// per tile (R14: barrier count cost-neutral), coalesced us8 stores.
// Scatter fused as R13 (~12us marginal). convert/gather/tail verbatim R13.
// Predicted: k_sg 75 -> ~35-50us, FETCH ~27->~19MB, VGPR ~110-130,
// total 262 -> ~225-240. If k_sg >= 60: intensity theory dead.
// Dispatches: convert, sg, gather, tail (4).
// ---------------------------------------------------------------------------

typedef short short8 __attribute__((ext_vector_type(8)));
typedef float f32x4 __attribute__((ext_vector_type(4)));
typedef float float4v __attribute__((ext_vector_type(4)));
typedef unsigned short us8 __attribute__((ext_vector_type(8)));
typedef unsigned short us4 __attribute__((ext_vector_type(4)));

__device__ inline float bf2f(unsigned short h) {
    union { unsigned int u; float f; } v;
    v.u = ((unsigned int)h) << 16;
    return v.f;
}
__device__ inline unsigned short f2bf(float f) {
    union { float f; unsigned int u; } v;
    v.f = f;
    unsigned int r = v.u + 0x7FFFu + ((v.u >> 16) & 1u);  // RNE
    return (unsigned short)(r >> 16);
}

// ---- convert x + weights(col-major) -> bf16; head[]=-1, deg[]=0 -----------
// (verbatim R13)
__global__ __launch_bounds__(256) void k_convert(
    const float* __restrict__ x, const float* __restrict__ W_edge,
    const float* __restrict__ W_node, const float* __restrict__ W_ed,
    const float* __restrict__ W_f1,
    unsigned short* __restrict__ xb, unsigned short* __restrict__ WE2T,
    unsigned short* __restrict__ WnT, unsigned short* __restrict__ WdT,
    unsigned short* __restrict__ Wf1P, int* __restrict__ head,
    int* __restrict__ deg,
    int quads, int N)
{
    int i = blockIdx.x * 256 + threadIdx.x;
    if (i < quads) {
        float4v v = ((const float4v*)x)[i];
        us4 o;
        for (int j = 0; j < 4; ++j) o[j] = f2bf(v[j]);
        ((us4*)xb)[i] = o;
        return;
    }
    int j = i - quads;
    if (j < 65536) {                          // WE2T [512 c][128 k] = [Wa-Wb|Wb]^T
        int c = j & 511, k = j >> 9;
        float v;
        if (c < 256) v = W_edge[k * 256 + c] - W_edge[(k + 128) * 256 + c];
        else         v = W_edge[(k + 128) * 256 + (c - 256)];
        WE2T[c * 128 + k] = f2bf(v);
    } else if (j < 65536 + 32768) {           // WnT [256 c][128 k]
        int t = j - 65536;
        int c = t & 255, k = t >> 8;
        WnT[c * 128 + k] = f2bf(W_node[k * 256 + c]);
    } else if (j < 65536 + 65536) {           // WdT [128 c][256 k]
        int t = j - 65536 - 32768;
        int c = t & 127, k = t >> 7;
        WdT[c * 256 + k] = f2bf(W_ed[k * 128 + c]);
    } else if (j < 143360) {                  // Wf1P [32 c][384 kp] permuted
        int t = j - 65536 - 65536;
        int c = t & 31, kp = t >> 5;
        int w = kp / 96, idx = kp % 96;
        int korig;
        if (idx < 64) korig = (w + (idx >> 4) * 4) * 16 + (idx & 15);
        else          korig = 256 + (w + ((idx - 64) >> 4) * 4) * 16 + (idx & 15);
        Wf1P[c * 384 + kp] = f2bf(W_f1[korig * 32 + c]);
    } else {
        int t = j - 143360;
        if (t < N) { head[t] = -1; deg[t] = 0; }
    }
}

// ---- fused dispatch: padded-CSR build (1/3) + WIDE gemm (row-group/block) -
// b%3==2 -> scatter; else g = b - b/3 -> gemm row group (all 512 cols).
__global__ __launch_bounds__(512) void k_sg(
    const int* __restrict__ src, const int* __restrict__ dst,
    int* __restrict__ head, unsigned long long* __restrict__ next2,
    int* __restrict__ deg, int* __restrict__ adj,
    const unsigned short* __restrict__ xb,     // [N][128] bf16
    const unsigned short* __restrict__ WE2T,   // [512][128] bf16 col-major
    const float* __restrict__ b_edge,          // [256] fp32
    unsigned short* __restrict__ T,            // [N][512]
    int E, int N, int row_tiles, int scat_blocks, int gemm_blocks)
{
    __shared__ unsigned short st[2][16 * 524];
    int b = blockIdx.x;
    if (b % 3 == 2) {                          // scatter pass: padded CSR
        int sb_id = b / 3;
        if (sb_id >= scat_blocks) return;
        int i = sb_id * 512 + threadIdx.x;
        if (i >= E) return;
        int s = src[i], d = dst[i];
        if ((unsigned)d >= (unsigned)N || (unsigned)s >= (unsigned)N) return;
        int pos = atomicAdd(&deg[d], 1);
        if (pos < 32) {
            adj[(size_t)d * 32 + pos] = s;
        } else {                               // overflow: linked list
            int old = atomicExch(&head[d], i);
            next2[i] = ((unsigned long long)(unsigned)s << 32) | (unsigned)old;
        }
        return;
    }
    int g = b - b / 3;                         // gemm row-group id
    if (g >= gemm_blocks) return;

    const int lane = threadIdx.x & 63;
    const int wave = threadIdx.x >> 6;         // 0..7, owns cols [wave*64,+64)
    const int quad = lane >> 4;
    const int col16 = lane & 15;
    const int tid = threadIdx.x;

    // persistent B fragments: 4 col-chunks x 4 k-steps = 64 VGPR
    short8 bf[4][4];
    float bias[4];
#pragma unroll
    for (int cc = 0; cc < 4; ++cc) {
        int col = wave * 64 + cc * 16 + col16;
        bias[cc] = (col < 256) ? b_edge[col] : 0.f;
#pragma unroll
        for (int ks = 0; ks < 4; ++ks)
            bf[cc][ks] = *(const short8*)(WE2T + (size_t)col * 128 + ks * 32 + quad * 8);
    }

    int tmax = row_tiles - g * 8;              // block-uniform
    if (tmax > 8) tmax = 8;

    for (int t = 0; t < 8; ++t) {
        if (t >= tmax) break;                  // uniform: safe with barriers
        int r0 = (g * 8 + t) * 16;
        int arow = r0 + col16;
        if (arow >= N) arow = N - 1;

        // A-fragment: 4 loads feed 16 MFMAs
        short8 a[4];
        const unsigned short* ap = xb + (size_t)arow * 128 + quad * 8;
#pragma unroll
        for (int ks = 0; ks < 4; ++ks) a[ks] = *(const short8*)(ap + ks * 32);

        unsigned short* sbuf = st[t & 1];
#pragma unroll
        for (int cc = 0; cc < 4; ++cc) {
            f32x4 acc = {0.f, 0.f, 0.f, 0.f};
#pragma unroll
            for (int ks = 0; ks < 4; ++ks)
                acc = __builtin_amdgcn_mfma_f32_16x16x32_bf16(a[ks], bf[cc][ks], acc, 0, 0, 0);
#pragma unroll
            for (int r = 0; r < 4; ++r)
                sbuf[(quad * 4 + r) * 524 + wave * 64 + cc * 16 + col16] =
                    f2bf(acc[r] + bias[cc]);
        }

        __syncthreads();                       // one barrier per tile

        // store tile: 1024 us8-chunks, 512 threads x 2
#pragma unroll
        for (int p = 0; p < 2; ++p) {
            int chunk = tid + p * 512;
            int row = chunk >> 6;              // 0..15
            int cpos = (chunk & 63) * 8;       // 0..504
            if (r0 + row < N) {
                us8 v = *(const us8*)(sbuf + row * 524 + cpos);
                *(us8*)(T + (size_t)(r0 + row) * 512 + cpos) = v;
            }
        }
    }
}

// ---- Gather: half-wave per node over padded-CSR adjacency (verbatim R13) --
__global__ __launch_bounds__(256) void k_gather(
    unsigned short* __restrict__ T,          // [N][512]: P|Q -> EA over P
    const unsigned short* __restrict__ xb,   // [N][128]
    unsigned short* __restrict__ XA,         // [N][128]
    const int* __restrict__ deg,
    const int* __restrict__ adj,             // [N][32]
    const int* __restrict__ head,
    const unsigned long long* __restrict__ next2, int N)
{
    int wave = threadIdx.x >> 6;
    int lane = threadIdx.x & 63;
    int half = lane >> 5;
    int c = lane & 31;
    int n = blockIdx.x * 8 + wave * 2 + half;
    bool act = n < N;
    int nn = act ? n : N - 1;
    int c8 = c * 8, c4 = c * 4;

    us8 pv = *(const us8*)(T + (size_t)nn * 512 + c8);
    float p[8];
    for (int j = 0; j < 8; ++j) p[j] = bf2f(pv[j]);
    float aE[8] = {0, 0, 0, 0, 0, 0, 0, 0};
    float aX[4] = {0, 0, 0, 0};

    int dg = act ? deg[n] : 0;                 // uniform within half-wave
    int adjv = adj[(size_t)nn * 32 + c];       // one coalesced 4B/lane read
    int m = dg < 32 ? dg : 32;

    int k = 0;
    for (; k + 1 < m; k += 2) {                // 2-way unroll: independent loads
        int s0 = __shfl(adjv, k, 32);
        int s1 = __shfl(adjv, k + 1, 32);
        us8 q0 = *(const us8*)(T + (size_t)s0 * 512 + 256 + c8);
        us8 q1 = *(const us8*)(T + (size_t)s1 * 512 + 256 + c8);
        us4 x0 = *(const us4*)(xb + (size_t)s0 * 128 + c4);
        us4 x1 = *(const us4*)(xb + (size_t)s1 * 128 + c4);
        for (int j = 0; j < 8; ++j) {
            aE[j] += fmaxf(p[j] + bf2f(q0[j]), 0.f);
            aE[j] += fmaxf(p[j] + bf2f(q1[j]), 0.f);
        }
        for (int j = 0; j < 4; ++j)
            aX[j] += bf2f(x0[j]) + bf2f(x1[j]);
    }
    if (k < m) {
        int s0 = __shfl(adjv, k, 32);
        us8 q0 = *(const us8*)(T + (size_t)s0 * 512 + 256 + c8);
        us4 x0 = *(const us4*)(xb + (size_t)s0 * 128 + c4);
        for (int j = 0; j < 8; ++j) aE[j] += fmaxf(p[j] + bf2f(q0[j]), 0.f);
        for (int j = 0; j < 4; ++j) aX[j] += bf2f(x0[j]);
    }

    // Overflow fallback (deg > 32): walk residual linked list.
    int cur = (act && dg > 32) ? head[n] : -1;
    while (__any(cur >= 0)) {
        bool v = cur >= 0;
        int safe = v ? cur : 0;
        unsigned long long e2 = next2[safe];
        int s = (int)(e2 >> 32);
        float mm = v ? 1.f : 0.f;
        const unsigned short* tb = T + (size_t)s * 512;
        us8 qv = *(const us8*)(tb + 256 + c8);
        us4 xv = *(const us4*)(xb + (size_t)s * 128 + c4);
        for (int j = 0; j < 8; ++j)
            aE[j] += mm * fmaxf(p[j] + bf2f(qv[j]), 0.f);
        for (int j = 0; j < 4; ++j)
            aX[j] += mm * bf2f(xv[j]);
        cur = v ? (int)(unsigned)(e2 & 0xFFFFFFFFull) : -1;
    }

    if (act) {
        us8 ev;
        for (int j = 0; j < 8; ++j) ev[j] = f2bf(aE[j]);
        *(us8*)(T + (size_t)n * 512 + c8) = ev;       // EA over own P slot: safe
        us4 xo;
        for (int j = 0; j < 4; ++j) xo[j] = f2bf(aX[j]);
        *(us4*)(XA + (size_t)n * 128 + c4) = xo;
    }
}

// ---- Fused tail: persistent-weight multi-tile blocks (verbatim R13) -------
__global__ __launch_bounds__(256, 2) void k_tail(
    const unsigned short* __restrict__ T,    // EA in cols 0-255
    const unsigned short* __restrict__ XA,   // [N][128]
    const unsigned short* __restrict__ WnT,  // [256 c][128 k] col-major
    const unsigned short* __restrict__ WdT,  // [128 c][256 k] col-major
    const unsigned short* __restrict__ Wf1P, // [32 c][384 kp] permuted
    const float* __restrict__ b_node, const float* __restrict__ b_ed,
    const float* __restrict__ b_f1, const float* __restrict__ W_f2,
    const float* __restrict__ b_f2,
    float* __restrict__ out, int N, int row_tiles, int tiles_per_block)
{
    __shared__ unsigned short hslice[4][16 * 100];  // per-wave h (bf16), pad 100
    __shared__ float red[4][16][33];                // MLP partials, pad 33
    const int wave = threadIdx.x >> 6;
    const int lane = threadIdx.x & 63;
    const int quad = lane >> 4;
    const int col16 = lane & 15;

    // ---- persistent B fragments (loaded once per block) ----
    short8 bn[4][4], be[2][8], bfr[2][3];
    float bias_n[4], bias_e[2];
#pragma unroll
    for (int ci = 0; ci < 4; ++ci) {
        int col = (wave + ci * 4) * 16 + col16;
        bias_n[ci] = b_node[col];
#pragma unroll
        for (int ks = 0; ks < 4; ++ks)
            bn[ci][ks] = *(const short8*)(WnT + (size_t)col * 128 + ks * 32 + quad * 8);
    }
#pragma unroll
    for (int ci = 0; ci < 2; ++ci) {
        int col = (wave + ci * 4) * 16 + col16;
        bias_e[ci] = b_ed[col];
#pragma unroll
        for (int ks = 0; ks < 8; ++ks)
            be[ci][ks] = *(const short8*)(WdT + (size_t)col * 256 + ks * 32 + quad * 8);
    }
#pragma unroll
    for (int cc = 0; cc < 2; ++cc) {
        int c = cc * 16 + col16;
#pragma unroll
        for (int ks = 0; ks < 3; ++ks)
            bfr[cc][ks] = *(const short8*)(Wf1P + (size_t)c * 384 + wave * 96 + ks * 32 + quad * 8);
    }

    unsigned short* hw = &hslice[wave][0];
    int t0 = blockIdx.x * tiles_per_block;
    int t1 = t0 + tiles_per_block;
    if (t1 > row_tiles) t1 = row_tiles;

    for (int tile = t0; tile < t1; ++tile) {
        int r0 = tile * 16;
        int arow = r0 + col16;
        if (arow >= N) arow = N - 1;

        // --- node path: h[:,0:256], this wave's 4 chunks ---
        short8 ax[4];
        {
            const unsigned short* xap = XA + (size_t)arow * 128 + quad * 8;
#pragma unroll
            for (int ks = 0; ks < 4; ++ks) ax[ks] = *(const short8*)(xap + ks * 32);
        }
#pragma unroll
        for (int ci = 0; ci < 4; ++ci) {
            f32x4 acc = {0.f, 0.f, 0.f, 0.f};
#pragma unroll
            for (int ks = 0; ks < 4; ++ks)
                acc = __builtin_amdgcn_mfma_f32_16x16x32_bf16(ax[ks], bn[ci][ks], acc, 0, 0, 0);
#pragma unroll
            for (int r = 0; r < 4; ++r)
                hw[(quad * 4 + r) * 100 + ci * 16 + col16] =
                    f2bf(fmaxf(acc[r] + bias_n[ci], 0.f));
        }

        // --- edge path: h[:,256:384], this wave's 2 chunks ---
        short8 ae[8];
        {
            const unsigned short* eap = T + (size_t)arow * 512 + quad * 8;
#pragma unroll
            for (int ks = 0; ks < 8; ++ks) ae[ks] = *(const short8*)(eap + ks * 32);
        }
#pragma unroll
        for (int ci = 0; ci < 2; ++ci) {
            f32x4 acc = {0.f, 0.f, 0.f, 0.f};
#pragma unroll
            for (int ks = 0; ks < 8; ++ks)
                acc = __builtin_amdgcn_mfma_f32_16x16x32_bf16(ae[ks], be[ci][ks], acc, 0, 0, 0);
#pragma unroll
            for (int r = 0; r < 4; ++r)
                hw[(quad * 4 + r) * 100 + 64 + ci * 16 + col16] =
                    f2bf(fmaxf(acc[r] + bias_e[ci], 0.f));
        }

        // --- MLP partial over own 96-K slice (same-wave LDS, no barrier) ---
        f32x4 m0 = {0.f, 0.f, 0.f, 0.f}, m1 = {0.f, 0.f, 0.f, 0.f};
#pragma unroll
        for (int ks = 0; ks < 3; ++ks) {
            short8 a = *(const short8*)(hw + col16 * 100 + ks * 32 + quad * 8);
            m0 = __builtin_amdgcn_mfma_f32_16x16x32_bf16(a, bfr[0][ks], m0, 0, 0, 0);
            m1 = __builtin_amdgcn_mfma_f32_16x16x32_bf16(a, bfr[1][ks], m1, 0, 0, 0);
        }
#pragma unroll
        for (int r = 0; r < 4; ++r) {
            red[wave][quad * 4 + r][col16] = m0[r];
            red[wave][quad * 4 + r][16 + col16] = m1[r];
        }
        __syncthreads();

        // --- final reduce + MLP2 + sigmoid on wave 0 ---
        if (wave == 0) {
            int row = col16, g = quad;          // each lane: 8 cols of one row
            float s = 0.f;
#pragma unroll
            for (int cc = 0; cc < 8; ++cc) {
                int col = g * 8 + cc;
                float v = red[0][row][col] + red[1][row][col] +
                          red[2][row][col] + red[3][row][col] + b_f1[col];
                s += fmaxf(v, 0.f) * W_f2[col];
            }
            s += __shfl_xor(s, 16, 64);
            s += __shfl_xor(s, 32, 64);
            if (g == 0 && r0 + row < N) {
                float v = s + b_f2[0];
                out[r0 + row] = 1.f / (1.f + __expf(-v));
            }
        }
        __syncthreads();   // red reused next tile
    }
}

extern "C" void kernel_launch(void* const* d_in, const int* in_sizes, int n_in,
                              void* d_out, int out_size, void* d_ws, size_t ws_size,
                              hipStream_t stream) {
    const float* x      = (const float*)d_in[0];
    const int*   ei     = (const int*)d_in[1];
    // d_in[2] = e (unused)
    const float* W_node = (const float*)d_in[3];
    const float* b_node = (const float*)d_in[4];
    const float* W_edge = (const float*)d_in[5];
    const float* b_edge = (const float*)d_in[6];
    const float* W_ed   = (const float*)d_in[7];
    const float* b_ed   = (const float*)d_in[8];
    const float* W_f1   = (const float*)d_in[9];
    const float* b_f1   = (const float*)d_in[10];
    const float* W_f2   = (const float*)d_in[11];
    const float* b_f2   = (const float*)d_in[12];

    const int N = in_sizes[0] / 128;
    const int E = in_sizes[1] / 2;
    const int* src = ei;
    const int* dst = ei + E;

    char* ws = (char*)d_ws;
    size_t off = 0;
    auto alloc = [&](size_t bytes) { size_t o = off; off += (bytes + 255) & ~(size_t)255; return o; };
    unsigned short* xb   = (unsigned short*)(ws + alloc((size_t)N * 128 * 2));
    unsigned short* WE2T = (unsigned short*)(ws + alloc(512 * 128 * 2));
    unsigned short* WnT  = (unsigned short*)(ws + alloc(256 * 128 * 2));
    unsigned short* WdT  = (unsigned short*)(ws + alloc(128 * 256 * 2));
    unsigned short* Wf1P = (unsigned short*)(ws + alloc(32 * 384 * 2));
    unsigned short* T    = (unsigned short*)(ws + alloc((size_t)N * 512 * 2));
    unsigned short* XA   = (unsigned short*)(ws + alloc((size_t)N * 128 * 2));
    int* head            = (int*)(ws + alloc((size_t)N * 4));
    unsigned long long* next2 = (unsigned long long*)(ws + alloc((size_t)E * 8));
    int* deg             = (int*)(ws + alloc((size_t)N * 4));
    int* adj             = (int*)(ws + alloc((size_t)N * 32 * 4));

    const int row_tiles   = (N + 15) / 16;
    const int row_groups  = (row_tiles + 7) / 8;
    const int quads       = N * 128 / 4;
    const int conv_items  = quads + 143360 + N;
    const int scat_blocks = (E + 511) / 512;
    const int gemm_blocks = row_groups;            // wide blocks: 1 per group
    int grid3 = scat_blocks * 3;
    int need_g = ((gemm_blocks + 1) / 2) * 3;
    if (need_g > grid3) grid3 = need_g;

    k_convert<<<(conv_items + 255) / 256, 256, 0, stream>>>(
        x, W_edge, W_node, W_ed, W_f1, xb, WE2T, WnT, WdT, Wf1P, head, deg,
        quads, N);
    k_sg<<<grid3, 512, 0, stream>>>(
        src, dst, head, next2, deg, adj, xb, WE2T, b_edge, T, E, N, row_tiles,
        scat_blocks, gemm_blocks);
    k_gather<<<(N + 7) / 8, 256, 0, stream>>>(T, xb, XA, deg, adj, head, next2, N);

    int tail_blocks = 512;
    if (tail_blocks > row_tiles) tail_blocks = row_tiles;
    int tpb = (row_tiles + tail_blocks - 1) / tail_blocks;
    k_tail<<<tail_blocks, 256, 0, stream>>>(
        T, XA, WnT, WdT, Wf1P, b_node, b_ed, b_f1, W_f2, b_f2,
        (float*)d_out, N, row_tiles, tpb);
}

// Round 13
// 229.789 us; speedup vs baseline: 1.7005x; 1.0143x over previous
//
#include <hip/hip_runtime.h>
#include <stdint.h>

// ---------------------------------------------------------------------------
// EdgeNodeGCN on MI355X (gfx950). Inputs fp32, edge_index int32, output fp32.
// Factorization:
//   P[n]  = x[n] @ (Wa - Wb) + b_edge   (Wa = W_edge[0:128], Wb = W_edge[128:256])
//   Q[n]  = x[n] @ Wb
//   msg(e)= relu(P[dst] + Q[src]);  edge_agg[d] = sum msg
//   XA[d] = sum_{e->d} x[src]           (segment_sum commutes with @W_node)
//   nodes = relu(XA @ W_node + b_node); edges = relu(edge_agg @ W_ed + b_ed)
//   out   = sigmoid(relu([nodes|edges] @ W_f1 + b_f1) @ W_f2 + b_f2)
//
// R22 vs R21 (233 us): wide-block gemm CONFIRMED (262->233, k_sg out of
// top-5). New leader k_gather 54us: FETCH 153MB, 3.6 TB/s (57% of
// achievable), VALU 36%, no over-fetch (all lines used; logical 307MB, L3
// absorbs half). Latency component remains: 2-way unroll = only 4 loads in
// flight, ~4 serial iterations at avg deg 8. ONE change: 4-WAY UNROLL of the
// edge loop (8 independent loads/iter, ~2 iters/node). VGPR ~+24, no occ
// cliff. Remainder loop for deg%4; overflow chain untouched; rest verbatim.
// Predicted: gather 54 -> ~38-45us, hbm 3.6 -> ~4.5-5.2 TB/s, FETCH same,
// total 233 -> ~215-222.
// Dispatches: convert, sg, gather, tail (4).
// ---------------------------------------------------------------------------

typedef short short8 __attribute__((ext_vector_type(8)));
typedef float f32x4 __attribute__((ext_vector_type(4)));
typedef float float4v __attribute__((ext_vector_type(4)));
typedef unsigned short us8 __attribute__((ext_vector_type(8)));
typedef unsigned short us4 __attribute__((ext_vector_type(4)));

__device__ inline float bf2f(unsigned short h) {
    union { unsigned int u; float f; } v;
    v.u = ((unsigned int)h) << 16;
    return v.f;
}
__device__ inline unsigned short f2bf(float f) {
    union { float f; unsigned int u; } v;
    v.f = f;
    unsigned int r = v.u + 0x7FFFu + ((v.u >> 16) & 1u);  // RNE
    return (unsigned short)(r >> 16);
}

// ---- convert x + weights(col-major) -> bf16; head[]=-1, deg[]=0 -----------
__global__ __launch_bounds__(256) void k_convert(
    const float* __restrict__ x, const float* __restrict__ W_edge,
    const float* __restrict__ W_node, const float* __restrict__ W_ed,
    const float* __restrict__ W_f1,
    unsigned short* __restrict__ xb, unsigned short* __restrict__ WE2T,
    unsigned short* __restrict__ WnT, unsigned short* __restrict__ WdT,
    unsigned short* __restrict__ Wf1P, int* __restrict__ head,
    int* __restrict__ deg,
    int quads, int N)
{
    int i = blockIdx.x * 256 + threadIdx.x;
    if (i < quads) {
        float4v v = ((const float4v*)x)[i];
        us4 o;
        for (int j = 0; j < 4; ++j) o[j] = f2bf(v[j]);
        ((us4*)xb)[i] = o;
        return;
    }
    int j = i - quads;
    if (j < 65536) {                          // WE2T [512 c][128 k] = [Wa-Wb|Wb]^T
        int c = j & 511, k = j >> 9;
        float v;
        if (c < 256) v = W_edge[k * 256 + c] - W_edge[(k + 128) * 256 + c];
        else         v = W_edge[(k + 128) * 256 + (c - 256)];
        WE2T[c * 128 + k] = f2bf(v);
    } else if (j < 65536 + 32768) {           // WnT [256 c][128 k]
        int t = j - 65536;
        int c = t & 255, k = t >> 8;
        WnT[c * 128 + k] = f2bf(W_node[k * 256 + c]);
    } else if (j < 65536 + 65536) {           // WdT [128 c][256 k]
        int t = j - 65536 - 32768;
        int c = t & 127, k = t >> 7;
        WdT[c * 256 + k] = f2bf(W_ed[k * 128 + c]);
    } else if (j < 143360) {                  // Wf1P [32 c][384 kp] permuted
        int t = j - 65536 - 65536;
        int c = t & 31, kp = t >> 5;
        int w = kp / 96, idx = kp % 96;
        int korig;
        if (idx < 64) korig = (w + (idx >> 4) * 4) * 16 + (idx & 15);
        else          korig = 256 + (w + ((idx - 64) >> 4) * 4) * 16 + (idx & 15);
        Wf1P[c * 384 + kp] = f2bf(W_f1[korig * 32 + c]);
    } else {
        int t = j - 143360;
        if (t < N) { head[t] = -1; deg[t] = 0; }
    }
}

// ---- fused dispatch: padded-CSR build (1/3) + WIDE gemm (row-group/block) -
__global__ __launch_bounds__(512) void k_sg(
    const int* __restrict__ src, const int* __restrict__ dst,
    int* __restrict__ head, unsigned long long* __restrict__ next2,
    int* __restrict__ deg, int* __restrict__ adj,
    const unsigned short* __restrict__ xb,     // [N][128] bf16
    const unsigned short* __restrict__ WE2T,   // [512][128] bf16 col-major
    const float* __restrict__ b_edge,          // [256] fp32
    unsigned short* __restrict__ T,            // [N][512]
    int E, int N, int row_tiles, int scat_blocks, int gemm_blocks)
{
    __shared__ unsigned short st[2][16 * 524];
    int b = blockIdx.x;
    if (b % 3 == 2) {                          // scatter pass: padded CSR
        int sb_id = b / 3;
        if (sb_id >= scat_blocks) return;
        int i = sb_id * 512 + threadIdx.x;
        if (i >= E) return;
        int s = src[i], d = dst[i];
        if ((unsigned)d >= (unsigned)N || (unsigned)s >= (unsigned)N) return;
        int pos = atomicAdd(&deg[d], 1);
        if (pos < 32) {
            adj[(size_t)d * 32 + pos] = s;
        } else {                               // overflow: linked list
            int old = atomicExch(&head[d], i);
            next2[i] = ((unsigned long long)(unsigned)s << 32) | (unsigned)old;
        }
        return;
    }
    int g = b - b / 3;                         // gemm row-group id
    if (g >= gemm_blocks) return;

    const int lane = threadIdx.x & 63;
    const int wave = threadIdx.x >> 6;         // 0..7, owns cols [wave*64,+64)
    const int quad = lane >> 4;
    const int col16 = lane & 15;
    const int tid = threadIdx.x;

    // persistent B fragments: 4 col-chunks x 4 k-steps = 64 VGPR
    short8 bf[4][4];
    float bias[4];
#pragma unroll
    for (int cc = 0; cc < 4; ++cc) {
        int col = wave * 64 + cc * 16 + col16;
        bias[cc] = (col < 256) ? b_edge[col] : 0.f;
#pragma unroll
        for (int ks = 0; ks < 4; ++ks)
            bf[cc][ks] = *(const short8*)(WE2T + (size_t)col * 128 + ks * 32 + quad * 8);
    }

    int tmax = row_tiles - g * 8;              // block-uniform
    if (tmax > 8) tmax = 8;

    for (int t = 0; t < 8; ++t) {
        if (t >= tmax) break;                  // uniform: safe with barriers
        int r0 = (g * 8 + t) * 16;
        int arow = r0 + col16;
        if (arow >= N) arow = N - 1;

        // A-fragment: 4 loads feed 16 MFMAs
        short8 a[4];
        const unsigned short* ap = xb + (size_t)arow * 128 + quad * 8;
#pragma unroll
        for (int ks = 0; ks < 4; ++ks) a[ks] = *(const short8*)(ap + ks * 32);

        unsigned short* sbuf = st[t & 1];
#pragma unroll
        for (int cc = 0; cc < 4; ++cc) {
            f32x4 acc = {0.f, 0.f, 0.f, 0.f};
#pragma unroll
            for (int ks = 0; ks < 4; ++ks)
                acc = __builtin_amdgcn_mfma_f32_16x16x32_bf16(a[ks], bf[cc][ks], acc, 0, 0, 0);
#pragma unroll
            for (int r = 0; r < 4; ++r)
                sbuf[(quad * 4 + r) * 524 + wave * 64 + cc * 16 + col16] =
                    f2bf(acc[r] + bias[cc]);
        }

        __syncthreads();                       // one barrier per tile

        // store tile: 1024 us8-chunks, 512 threads x 2
#pragma unroll
        for (int p = 0; p < 2; ++p) {
            int chunk = tid + p * 512;
            int row = chunk >> 6;              // 0..15
            int cpos = (chunk & 63) * 8;       // 0..504
            if (r0 + row < N) {
                us8 v = *(const us8*)(sbuf + row * 524 + cpos);
                *(us8*)(T + (size_t)(r0 + row) * 512 + cpos) = v;
            }
        }
    }
}

// ---- Gather: half-wave per node, 4-way unrolled edge loop -----------------
__global__ __launch_bounds__(256) void k_gather(
    unsigned short* __restrict__ T,          // [N][512]: P|Q -> EA over P
    const unsigned short* __restrict__ xb,   // [N][128]
    unsigned short* __restrict__ XA,         // [N][128]
    const int* __restrict__ deg,
    const int* __restrict__ adj,             // [N][32]
    const int* __restrict__ head,
    const unsigned long long* __restrict__ next2, int N)
{
    int wave = threadIdx.x >> 6;
    int lane = threadIdx.x & 63;
    int half = lane >> 5;
    int c = lane & 31;
    int n = blockIdx.x * 8 + wave * 2 + half;
    bool act = n < N;
    int nn = act ? n : N - 1;
    int c8 = c * 8, c4 = c * 4;

    us8 pv = *(const us8*)(T + (size_t)nn * 512 + c8);
    float p[8];
    for (int j = 0; j < 8; ++j) p[j] = bf2f(pv[j]);
    float aE[8] = {0, 0, 0, 0, 0, 0, 0, 0};
    float aX[4] = {0, 0, 0, 0};

    int dg = act ? deg[n] : 0;                 // uniform within half-wave
    int adjv = adj[(size_t)nn * 32 + c];       // one coalesced 4B/lane read
    int m = dg < 32 ? dg : 32;

    int k = 0;
    for (; k + 3 < m; k += 4) {                // 4-way unroll: 8 indep loads
        int s0 = __shfl(adjv, k, 32);
        int s1 = __shfl(adjv, k + 1, 32);
        int s2 = __shfl(adjv, k + 2, 32);
        int s3 = __shfl(adjv, k + 3, 32);
        us8 q0 = *(const us8*)(T + (size_t)s0 * 512 + 256 + c8);
        us8 q1 = *(const us8*)(T + (size_t)s1 * 512 + 256 + c8);
        us8 q2 = *(const us8*)(T + (size_t)s2 * 512 + 256 + c8);
        us8 q3 = *(const us8*)(T + (size_t)s3 * 512 + 256 + c8);
        us4 x0 = *(const us4*)(xb + (size_t)s0 * 128 + c4);
        us4 x1 = *(const us4*)(xb + (size_t)s1 * 128 + c4);
        us4 x2 = *(const us4*)(xb + (size_t)s2 * 128 + c4);
        us4 x3 = *(const us4*)(xb + (size_t)s3 * 128 + c4);
        for (int j = 0; j < 8; ++j) {
            aE[j] += fmaxf(p[j] + bf2f(q0[j]), 0.f);
            aE[j] += fmaxf(p[j] + bf2f(q1[j]), 0.f);
            aE[j] += fmaxf(p[j] + bf2f(q2[j]), 0.f);
            aE[j] += fmaxf(p[j] + bf2f(q3[j]), 0.f);
        }
        for (int j = 0; j < 4; ++j)
            aX[j] += (bf2f(x0[j]) + bf2f(x1[j])) + (bf2f(x2[j]) + bf2f(x3[j]));
    }
    for (; k < m; ++k) {                       // remainder
        int s0 = __shfl(adjv, k, 32);
        us8 q0 = *(const us8*)(T + (size_t)s0 * 512 + 256 + c8);
        us4 x0 = *(const us4*)(xb + (size_t)s0 * 128 + c4);
        for (int j = 0; j < 8; ++j) aE[j] += fmaxf(p[j] + bf2f(q0[j]), 0.f);
        for (int j = 0; j < 4; ++j) aX[j] += bf2f(x0[j]);
    }

    // Overflow fallback (deg > 32): walk residual linked list.
    int cur = (act && dg > 32) ? head[n] : -1;
    while (__any(cur >= 0)) {
        bool v = cur >= 0;
        int safe = v ? cur : 0;
        unsigned long long e2 = next2[safe];
        int s = (int)(e2 >> 32);
        float mm = v ? 1.f : 0.f;
        const unsigned short* tb = T + (size_t)s * 512;
        us8 qv = *(const us8*)(tb + 256 + c8);
        us4 xv = *(const us4*)(xb + (size_t)s * 128 + c4);
        for (int j = 0; j < 8; ++j)
            aE[j] += mm * fmaxf(p[j] + bf2f(qv[j]), 0.f);
        for (int j = 0; j < 4; ++j)
            aX[j] += mm * bf2f(xv[j]);
        cur = v ? (int)(unsigned)(e2 & 0xFFFFFFFFull) : -1;
    }

    if (act) {
        us8 ev;
        for (int j = 0; j < 8; ++j) ev[j] = f2bf(aE[j]);
        *(us8*)(T + (size_t)n * 512 + c8) = ev;       // EA over own P slot: safe
        us4 xo;
        for (int j = 0; j < 4; ++j) xo[j] = f2bf(aX[j]);
        *(us4*)(XA + (size_t)n * 128 + c4) = xo;
    }
}

// ---- Fused tail: persistent-weight multi-tile blocks ----------------------
__global__ __launch_bounds__(256, 2) void k_tail(
    const unsigned short* __restrict__ T,    // EA in cols 0-255
    const unsigned short* __restrict__ XA,   // [N][128]
    const unsigned short* __restrict__ WnT,  // [256 c][128 k] col-major
    const unsigned short* __restrict__ WdT,  // [128 c][256 k] col-major
    const unsigned short* __restrict__ Wf1P, // [32 c][384 kp] permuted
    const float* __restrict__ b_node, const float* __restrict__ b_ed,
    const float* __restrict__ b_f1, const float* __restrict__ W_f2,
    const float* __restrict__ b_f2,
    float* __restrict__ out, int N, int row_tiles, int tiles_per_block)
{
    __shared__ unsigned short hslice[4][16 * 100];  // per-wave h (bf16), pad 100
    __shared__ float red[4][16][33];                // MLP partials, pad 33
    const int wave = threadIdx.x >> 6;
    const int lane = threadIdx.x & 63;
    const int quad = lane >> 4;
    const int col16 = lane & 15;

    // ---- persistent B fragments (loaded once per block) ----
    short8 bn[4][4], be[2][8], bfr[2][3];
    float bias_n[4], bias_e[2];
#pragma unroll
    for (int ci = 0; ci < 4; ++ci) {
        int col = (wave + ci * 4) * 16 + col16;
        bias_n[ci] = b_node[col];
#pragma unroll
        for (int ks = 0; ks < 4; ++ks)
            bn[ci][ks] = *(const short8*)(WnT + (size_t)col * 128 + ks * 32 + quad * 8);
    }
#pragma unroll
    for (int ci = 0; ci < 2; ++ci) {
        int col = (wave + ci * 4) * 16 + col16;
        bias_e[ci] = b_ed[col];
#pragma unroll
        for (int ks = 0; ks < 8; ++ks)
            be[ci][ks] = *(const short8*)(WdT + (size_t)col * 256 + ks * 32 + quad * 8);
    }
#pragma unroll
    for (int cc = 0; cc < 2; ++cc) {
        int c = cc * 16 + col16;
#pragma unroll
        for (int ks = 0; ks < 3; ++ks)
            bfr[cc][ks] = *(const short8*)(Wf1P + (size_t)c * 384 + wave * 96 + ks * 32 + quad * 8);
    }

    unsigned short* hw = &hslice[wave][0];
    int t0 = blockIdx.x * tiles_per_block;
    int t1 = t0 + tiles_per_block;
    if (t1 > row_tiles) t1 = row_tiles;

    for (int tile = t0; tile < t1; ++tile) {
        int r0 = tile * 16;
        int arow = r0 + col16;
        if (arow >= N) arow = N - 1;

        // --- node path: h[:,0:256], this wave's 4 chunks ---
        short8 ax[4];
        {
            const unsigned short* xap = XA + (size_t)arow * 128 + quad * 8;
#pragma unroll
            for (int ks = 0; ks < 4; ++ks) ax[ks] = *(const short8*)(xap + ks * 32);
        }
#pragma unroll
        for (int ci = 0; ci < 4; ++ci) {
            f32x4 acc = {0.f, 0.f, 0.f, 0.f};
#pragma unroll
            for (int ks = 0; ks < 4; ++ks)
                acc = __builtin_amdgcn_mfma_f32_16x16x32_bf16(ax[ks], bn[ci][ks], acc, 0, 0, 0);
#pragma unroll
            for (int r = 0; r < 4; ++r)
                hw[(quad * 4 + r) * 100 + ci * 16 + col16] =
                    f2bf(fmaxf(acc[r] + bias_n[ci], 0.f));
        }

        // --- edge path: h[:,256:384], this wave's 2 chunks ---
        short8 ae[8];
        {
            const unsigned short* eap = T + (size_t)arow * 512 + quad * 8;
#pragma unroll
            for (int ks = 0; ks < 8; ++ks) ae[ks] = *(const short8*)(eap + ks * 32);
        }
#pragma unroll
        for (int ci = 0; ci < 2; ++ci) {
            f32x4 acc = {0.f, 0.f, 0.f, 0.f};
#pragma unroll
            for (int ks = 0; ks < 8; ++ks)
                acc = __builtin_amdgcn_mfma_f32_16x16x32_bf16(ae[ks], be[ci][ks], acc, 0, 0, 0);
#pragma unroll
            for (int r = 0; r < 4; ++r)
                hw[(quad * 4 + r) * 100 + 64 + ci * 16 + col16] =
                    f2bf(fmaxf(acc[r] + bias_e[ci], 0.f));
        }

        // --- MLP partial over own 96-K slice (same-wave LDS, no barrier) ---
        f32x4 m0 = {0.f, 0.f, 0.f, 0.f}, m1 = {0.f, 0.f, 0.f, 0.f};
#pragma unroll
        for (int ks = 0; ks < 3; ++ks) {
            short8 a = *(const short8*)(hw + col16 * 100 + ks * 32 + quad * 8);
            m0 = __builtin_amdgcn_mfma_f32_16x16x32_bf16(a, bfr[0][ks], m0, 0, 0, 0);
            m1 = __builtin_amdgcn_mfma_f32_16x16x32_bf16(a, bfr[1][ks], m1, 0, 0, 0);
        }
#pragma unroll
        for (int r = 0; r < 4; ++r) {
            red[wave][quad * 4 + r][col16] = m0[r];
            red[wave][quad * 4 + r][16 + col16] = m1[r];
        }
        __syncthreads();

        // --- final reduce + MLP2 + sigmoid on wave 0 ---
        if (wave == 0) {
            int row = col16, g = quad;          // each lane: 8 cols of one row
            float s = 0.f;
#pragma unroll
            for (int cc = 0; cc < 8; ++cc) {
                int col = g * 8 + cc;
                float v = red[0][row][col] + red[1][row][col] +
                          red[2][row][col] + red[3][row][col] + b_f1[col];
                s += fmaxf(v, 0.f) * W_f2[col];
            }
            s += __shfl_xor(s, 16, 64);
            s += __shfl_xor(s, 32, 64);
            if (g == 0 && r0 + row < N) {
                float v = s + b_f2[0];
                out[r0 + row] = 1.f / (1.f + __expf(-v));
            }
        }
        __syncthreads();   // red reused next tile
    }
}

extern "C" void kernel_launch(void* const* d_in, const int* in_sizes, int n_in,
                              void* d_out, int out_size, void* d_ws, size_t ws_size,
                              hipStream_t stream) {
    const float* x      = (const float*)d_in[0];
    const int*   ei     = (const int*)d_in[1];
    // d_in[2] = e (unused)
    const float* W_node = (const float*)d_in[3];
    const float* b_node = (const float*)d_in[4];
    const float* W_edge = (const float*)d_in[5];
    const float* b_edge = (const float*)d_in[6];
    const float* W_ed   = (const float*)d_in[7];
    const float* b_ed   = (const float*)d_in[8];
    const float* W_f1   = (const float*)d_in[9];
    const float* b_f1   = (const float*)d_in[10];
    const float* W_f2   = (const float*)d_in[11];
    const float* b_f2   = (const float*)d_in[12];

    const int N = in_sizes[0] / 128;
    const int E = in_sizes[1] / 2;
    const int* src = ei;
    const int* dst = ei + E;

    char* ws = (char*)d_ws;
    size_t off = 0;
    auto alloc = [&](size_t bytes) { size_t o = off; off += (bytes + 255) & ~(size_t)255; return o; };
    unsigned short* xb   = (unsigned short*)(ws + alloc((size_t)N * 128 * 2));
    unsigned short* WE2T = (unsigned short*)(ws + alloc(512 * 128 * 2));
    unsigned short* WnT  = (unsigned short*)(ws + alloc(256 * 128 * 2));
    unsigned short* WdT  = (unsigned short*)(ws + alloc(128 * 256 * 2));
    unsigned short* Wf1P = (unsigned short*)(ws + alloc(32 * 384 * 2));
    unsigned short* T    = (unsigned short*)(ws + alloc((size_t)N * 512 * 2));
    unsigned short* XA   = (unsigned short*)(ws + alloc((size_t)N * 128 * 2));
    int* head            = (int*)(ws + alloc((size_t)N * 4));
    unsigned long long* next2 = (unsigned long long*)(ws + alloc((size_t)E * 8));
    int* deg             = (int*)(ws + alloc((size_t)N * 4));
    int* adj             = (int*)(ws + alloc((size_t)N * 32 * 4));

    const int row_tiles   = (N + 15) / 16;
    const int row_groups  = (row_tiles + 7) / 8;
    const int quads       = N * 128 / 4;
    const int conv_items  = quads + 143360 + N;
    const int scat_blocks = (E + 511) / 512;
    const int gemm_blocks = row_groups;            // wide blocks: 1 per group
    int grid3 = scat_blocks * 3;
    int need_g = ((gemm_blocks + 1) / 2) * 3;
    if (need_g > grid3) grid3 = need_g;

    k_convert<<<(conv_items + 255) / 256, 256, 0, stream>>>(
        x, W_edge, W_node, W_ed, W_f1, xb, WE2T, WnT, WdT, Wf1P, head, deg,
        quads, N);
    k_sg<<<grid3, 512, 0, stream>>>(
        src, dst, head, next2, deg, adj, xb, WE2T, b_edge, T, E, N, row_tiles,
        scat_blocks, gemm_blocks);
    k_gather<<<(N + 7) / 8, 256, 0, stream>>>(T, xb, XA, deg, adj, head, next2, N);

    int tail_blocks = 512;
    if (tail_blocks > row_tiles) tail_blocks = row_tiles;
    int tpb = (row_tiles + tail_blocks - 1) / tail_blocks;
    k_tail<<<tail_blocks, 256, 0, stream>>>(
        T, XA, WnT, WdT, Wf1P, b_node, b_ed, b_f1, W_f2, b_f2,
        (float*)d_out, N, row_tiles, tpb);
}

// Round 14
// 217.593 us; speedup vs baseline: 1.7959x; 1.0560x over previous
//
#include <hip/hip_runtime.h>
#include <stdint.h>

// ---------------------------------------------------------------------------
// EdgeNodeGCN on MI355X (gfx950). Inputs fp32, edge_index int32, output fp32.
// Factorization:
//   P[n]  = x[n] @ (Wa - Wb) + b_edge   (Wa = W_edge[0:128], Wb = W_edge[128:256])
//   Q[n]  = x[n] @ Wb
//   msg(e)= relu(P[dst] + Q[src]);  edge_agg[d] = sum msg
//   XA[d] = sum_{e->d} x[src]           (segment_sum commutes with @W_node)
//   nodes = relu(XA @ W_node + b_node); edges = relu(edge_agg @ W_ed + b_ed)
//   out   = sigmoid(relu([nodes|edges] @ W_f1 + b_f1) @ W_f2 + b_f2)
//
// R23 vs R22 (230 us): 4-way unroll was NULL (53us, occ 60->39 offset the
// MLP gain) -> gather is THROUGHPUT-bound at ~3.7 TB/s fabric, not latency.
// Only byte reduction helps. EA/XA round trip = 77MB whose only purpose is
// crossing the gather->tail kernel boundary. FUSE gather INTO tail:
//   - per 16-row tile, quarter-wave (16 lanes) gathers one node's EA/XA
//     (2-way unrolled edge loop, int2 adj read, shfl width 16);
//   - stage in LDS xe[16][392] (cols 0-127 XA, 128-383 EA), one barrier;
//   - existing MFMA flow reads A-fragments from LDS. EA/XA never hit global.
//   - k_gather dispatch deleted. VGPR ~220 under launch_bounds(256,2).
// Also restored R16's coalesced weight-transpose writes in k_convert (R20's
// revert accidentally brought back the uncoalesced 2B-store version).
// Predicted: k_tailg 45-55us FETCH~155MB WRITE~1MB, conv -10us,
// total 230 -> ~195-205. If k_tailg >= 75: fusion failed, revert.
// Dispatches: convert, sg, tailg (3).
// ---------------------------------------------------------------------------

typedef short short8 __attribute__((ext_vector_type(8)));
typedef float f32x4 __attribute__((ext_vector_type(4)));
typedef float float4v __attribute__((ext_vector_type(4)));
typedef unsigned short us8 __attribute__((ext_vector_type(8)));
typedef unsigned short us4 __attribute__((ext_vector_type(4)));

__device__ inline float bf2f(unsigned short h) {
    union { unsigned int u; float f; } v;
    v.u = ((unsigned int)h) << 16;
    return v.f;
}
__device__ inline unsigned short f2bf(float f) {
    union { float f; unsigned int u; } v;
    v.f = f;
    unsigned int r = v.u + 0x7FFFu + ((v.u >> 16) & 1u);  // RNE
    return (unsigned short)(r >> 16);
}

// ---- convert x + weights -> bf16 (COALESCED writes); head/deg init --------
__global__ __launch_bounds__(256) void k_convert(
    const float* __restrict__ x, const float* __restrict__ W_edge,
    const float* __restrict__ W_node, const float* __restrict__ W_ed,
    const float* __restrict__ W_f1,
    unsigned short* __restrict__ xb, unsigned short* __restrict__ WE2T,
    unsigned short* __restrict__ WnT, unsigned short* __restrict__ WdT,
    unsigned short* __restrict__ Wf1P, int* __restrict__ head,
    int* __restrict__ deg,
    int quads, int N)
{
    int i = blockIdx.x * 256 + threadIdx.x;
    if (i < quads) {
        float4v v = ((const float4v*)x)[i];
        us4 o;
        for (int j = 0; j < 4; ++j) o[j] = f2bf(v[j]);
        ((us4*)xb)[i] = o;
        return;
    }
    int j = i - quads;
    if (j < 65536) {                          // WE2T [512 c][128 k]: write elem j
        int c = j >> 7, k = j & 127;
        float v;
        if (c < 256) v = W_edge[k * 256 + c] - W_edge[(k + 128) * 256 + c];
        else         v = W_edge[(k + 128) * 256 + (c - 256)];
        WE2T[j] = f2bf(v);
    } else if (j < 65536 + 32768) {           // WnT [256 c][128 k]
        int t = j - 65536;
        int c = t >> 7, k = t & 127;
        WnT[t] = f2bf(W_node[k * 256 + c]);
    } else if (j < 65536 + 65536) {           // WdT [128 c][256 k]
        int t = j - 65536 - 32768;
        int c = t >> 8, k = t & 255;
        WdT[t] = f2bf(W_ed[k * 128 + c]);
    } else if (j < 143360) {                  // Wf1P [32 c][384 kp] permuted
        int t = j - 65536 - 65536;
        int c = t / 384, kp = t - c * 384;
        int w = kp / 96, idx = kp % 96;
        int korig;
        if (idx < 64) korig = (w + (idx >> 4) * 4) * 16 + (idx & 15);
        else          korig = 256 + (w + ((idx - 64) >> 4) * 4) * 16 + (idx & 15);
        Wf1P[t] = f2bf(W_f1[korig * 32 + c]);
    } else {
        int t = j - 143360;
        if (t < N) { head[t] = -1; deg[t] = 0; }
    }
}

// ---- fused dispatch: padded-CSR build (1/3) + WIDE gemm (row-group/block) -
__global__ __launch_bounds__(512) void k_sg(
    const int* __restrict__ src, const int* __restrict__ dst,
    int* __restrict__ head, unsigned long long* __restrict__ next2,
    int* __restrict__ deg, int* __restrict__ adj,
    const unsigned short* __restrict__ xb,     // [N][128] bf16
    const unsigned short* __restrict__ WE2T,   // [512][128] bf16 col-major
    const float* __restrict__ b_edge,          // [256] fp32
    unsigned short* __restrict__ T,            // [N][512]
    int E, int N, int row_tiles, int scat_blocks, int gemm_blocks)
{
    __shared__ unsigned short st[2][16 * 524];
    int b = blockIdx.x;
    if (b % 3 == 2) {                          // scatter pass: padded CSR
        int sb_id = b / 3;
        if (sb_id >= scat_blocks) return;
        int i = sb_id * 512 + threadIdx.x;
        if (i >= E) return;
        int s = src[i], d = dst[i];
        if ((unsigned)d >= (unsigned)N || (unsigned)s >= (unsigned)N) return;
        int pos = atomicAdd(&deg[d], 1);
        if (pos < 32) {
            adj[(size_t)d * 32 + pos] = s;
        } else {                               // overflow: linked list
            int old = atomicExch(&head[d], i);
            next2[i] = ((unsigned long long)(unsigned)s << 32) | (unsigned)old;
        }
        return;
    }
    int g = b - b / 3;                         // gemm row-group id
    if (g >= gemm_blocks) return;

    const int lane = threadIdx.x & 63;
    const int wave = threadIdx.x >> 6;         // 0..7, owns cols [wave*64,+64)
    const int quad = lane >> 4;
    const int col16 = lane & 15;
    const int tid = threadIdx.x;

    // persistent B fragments: 4 col-chunks x 4 k-steps = 64 VGPR
    short8 bf[4][4];
    float bias[4];
#pragma unroll
    for (int cc = 0; cc < 4; ++cc) {
        int col = wave * 64 + cc * 16 + col16;
        bias[cc] = (col < 256) ? b_edge[col] : 0.f;
#pragma unroll
        for (int ks = 0; ks < 4; ++ks)
            bf[cc][ks] = *(const short8*)(WE2T + (size_t)col * 128 + ks * 32 + quad * 8);
    }

    int tmax = row_tiles - g * 8;              // block-uniform
    if (tmax > 8) tmax = 8;

    for (int t = 0; t < 8; ++t) {
        if (t >= tmax) break;                  // uniform: safe with barriers
        int r0 = (g * 8 + t) * 16;
        int arow = r0 + col16;
        if (arow >= N) arow = N - 1;

        // A-fragment: 4 loads feed 16 MFMAs
        short8 a[4];
        const unsigned short* ap = xb + (size_t)arow * 128 + quad * 8;
#pragma unroll
        for (int ks = 0; ks < 4; ++ks) a[ks] = *(const short8*)(ap + ks * 32);

        unsigned short* sbuf = st[t & 1];
#pragma unroll
        for (int cc = 0; cc < 4; ++cc) {
            f32x4 acc = {0.f, 0.f, 0.f, 0.f};
#pragma unroll
            for (int ks = 0; ks < 4; ++ks)
                acc = __builtin_amdgcn_mfma_f32_16x16x32_bf16(a[ks], bf[cc][ks], acc, 0, 0, 0);
#pragma unroll
            for (int r = 0; r < 4; ++r)
                sbuf[(quad * 4 + r) * 524 + wave * 64 + cc * 16 + col16] =
                    f2bf(acc[r] + bias[cc]);
        }

        __syncthreads();                       // one barrier per tile

        // store tile: 1024 us8-chunks, 512 threads x 2
#pragma unroll
        for (int p = 0; p < 2; ++p) {
            int chunk = tid + p * 512;
            int row = chunk >> 6;              // 0..15
            int cpos = (chunk & 63) * 8;       // 0..504
            if (r0 + row < N) {
                us8 v = *(const us8*)(sbuf + row * 524 + cpos);
                *(us8*)(T + (size_t)(r0 + row) * 512 + cpos) = v;
            }
        }
    }
}

// ---- Fused gather + tail: quarter-wave gather -> LDS -> MFMA --------------
// Per tile: 16 nodes gathered by 16 quarter-waves into xe[16][392]
// (cols 0-127 = XA, 128-383 = EA); barrier; node/edge GEMMs + MLP as before.
__global__ __launch_bounds__(256, 2) void k_tailg(
    const unsigned short* __restrict__ T,    // [N][512] P|Q (read-only)
    const unsigned short* __restrict__ xb,   // [N][128]
    const int* __restrict__ deg,
    const int* __restrict__ adj,             // [N][32]
    const int* __restrict__ head,
    const unsigned long long* __restrict__ next2,
    const unsigned short* __restrict__ WnT,  // [256 c][128 k] col-major
    const unsigned short* __restrict__ WdT,  // [128 c][256 k] col-major
    const unsigned short* __restrict__ Wf1P, // [32 c][384 kp] permuted
    const float* __restrict__ b_node, const float* __restrict__ b_ed,
    const float* __restrict__ b_f1, const float* __restrict__ W_f2,
    const float* __restrict__ b_f2,
    float* __restrict__ out, int N, int row_tiles, int tiles_per_block)
{
    __shared__ unsigned short hslice[4][16 * 100];  // per-wave h (bf16)
    __shared__ float red[4][16][33];                // MLP partials
    __shared__ unsigned short xe[16 * 392];         // XA|EA per tile
    const int wave = threadIdx.x >> 6;
    const int lane = threadIdx.x & 63;
    const int quad = lane >> 4;
    const int col16 = lane & 15;

    // ---- persistent B fragments (loaded once per block) ----
    short8 bn[4][4], be[2][8], bfr[2][3];
    float bias_n[4], bias_e[2];
#pragma unroll
    for (int ci = 0; ci < 4; ++ci) {
        int col = (wave + ci * 4) * 16 + col16;
        bias_n[ci] = b_node[col];
#pragma unroll
        for (int ks = 0; ks < 4; ++ks)
            bn[ci][ks] = *(const short8*)(WnT + (size_t)col * 128 + ks * 32 + quad * 8);
    }
#pragma unroll
    for (int ci = 0; ci < 2; ++ci) {
        int col = (wave + ci * 4) * 16 + col16;
        bias_e[ci] = b_ed[col];
#pragma unroll
        for (int ks = 0; ks < 8; ++ks)
            be[ci][ks] = *(const short8*)(WdT + (size_t)col * 256 + ks * 32 + quad * 8);
    }
#pragma unroll
    for (int cc = 0; cc < 2; ++cc) {
        int c = cc * 16 + col16;
#pragma unroll
        for (int ks = 0; ks < 3; ++ks)
            bfr[cc][ks] = *(const short8*)(Wf1P + (size_t)c * 384 + wave * 96 + ks * 32 + quad * 8);
    }

    unsigned short* hw = &hslice[wave][0];
    int t0 = blockIdx.x * tiles_per_block;
    int t1 = t0 + tiles_per_block;
    if (t1 > row_tiles) t1 = row_tiles;

    for (int tile = t0; tile < t1; ++tile) {
        int r0 = tile * 16;

        // ================= gather phase: quarter-wave per node =============
        {
            int qn = wave * 4 + quad;            // node-in-tile 0..15
            int n = r0 + qn;
            bool act = n < N;
            int nn = act ? n : N - 1;
            int c = col16;

            // P row cols [c*16, c*16+16)
            us8 pv0 = *(const us8*)(T + (size_t)nn * 512 + c * 16);
            us8 pv1 = *(const us8*)(T + (size_t)nn * 512 + c * 16 + 8);
            float p[16];
#pragma unroll
            for (int j = 0; j < 8; ++j) { p[j] = bf2f(pv0[j]); p[j + 8] = bf2f(pv1[j]); }
            float aE[16];
#pragma unroll
            for (int j = 0; j < 16; ++j) aE[j] = 0.f;
            float aX[8] = {0, 0, 0, 0, 0, 0, 0, 0};

            int dg = act ? deg[n] : 0;
            int2 av = ((const int2*)(adj + (size_t)nn * 32))[c];  // slots 2c,2c+1
            int m = dg < 32 ? dg : 32;

            int k = 0;
            for (; k + 1 < m; k += 2) {          // 2-way unroll
                int s0 = __shfl(av.x, k >> 1, 16);
                int s1 = __shfl(av.y, k >> 1, 16);
                us8 q0a = *(const us8*)(T + (size_t)s0 * 512 + 256 + c * 16);
                us8 q0b = *(const us8*)(T + (size_t)s0 * 512 + 256 + c * 16 + 8);
                us8 q1a = *(const us8*)(T + (size_t)s1 * 512 + 256 + c * 16);
                us8 q1b = *(const us8*)(T + (size_t)s1 * 512 + 256 + c * 16 + 8);
                us8 x0 = *(const us8*)(xb + (size_t)s0 * 128 + c * 8);
                us8 x1 = *(const us8*)(xb + (size_t)s1 * 128 + c * 8);
#pragma unroll
                for (int j = 0; j < 8; ++j) {
                    aE[j]     += fmaxf(p[j] + bf2f(q0a[j]), 0.f);
                    aE[j + 8] += fmaxf(p[j + 8] + bf2f(q0b[j]), 0.f);
                    aE[j]     += fmaxf(p[j] + bf2f(q1a[j]), 0.f);
                    aE[j + 8] += fmaxf(p[j + 8] + bf2f(q1b[j]), 0.f);
                    aX[j] += bf2f(x0[j]) + bf2f(x1[j]);
                }
            }
            if (k < m) {                         // remainder (slot k is even)
                int s0 = __shfl((k & 1) ? av.y : av.x, k >> 1, 16);
                us8 q0a = *(const us8*)(T + (size_t)s0 * 512 + 256 + c * 16);
                us8 q0b = *(const us8*)(T + (size_t)s0 * 512 + 256 + c * 16 + 8);
                us8 x0 = *(const us8*)(xb + (size_t)s0 * 128 + c * 8);
#pragma unroll
                for (int j = 0; j < 8; ++j) {
                    aE[j]     += fmaxf(p[j] + bf2f(q0a[j]), 0.f);
                    aE[j + 8] += fmaxf(p[j + 8] + bf2f(q0b[j]), 0.f);
                    aX[j] += bf2f(x0[j]);
                }
            }

            // overflow fallback (deg > 32): residual linked list
            int cur = (act && dg > 32) ? head[n] : -1;
            while (__any(cur >= 0)) {
                bool v = cur >= 0;
                int safe = v ? cur : 0;
                unsigned long long e2 = next2[safe];
                int s = (int)(e2 >> 32);
                float mm = v ? 1.f : 0.f;
                us8 qa = *(const us8*)(T + (size_t)s * 512 + 256 + c * 16);
                us8 qb = *(const us8*)(T + (size_t)s * 512 + 256 + c * 16 + 8);
                us8 xv = *(const us8*)(xb + (size_t)s * 128 + c * 8);
#pragma unroll
                for (int j = 0; j < 8; ++j) {
                    aE[j]     += mm * fmaxf(p[j] + bf2f(qa[j]), 0.f);
                    aE[j + 8] += mm * fmaxf(p[j + 8] + bf2f(qb[j]), 0.f);
                    aX[j] += mm * bf2f(xv[j]);
                }
                cur = v ? (int)(unsigned)(e2 & 0xFFFFFFFFull) : -1;
            }

            // write to xe: row qn; XA cols [c*8,+8), EA cols 128+[c*16,+16)
            unsigned short* xr = xe + qn * 392;
            us8 xo;
#pragma unroll
            for (int j = 0; j < 8; ++j) xo[j] = f2bf(aX[j]);
            *(us8*)(xr + c * 8) = xo;
            us8 e0, e1;
#pragma unroll
            for (int j = 0; j < 8; ++j) { e0[j] = f2bf(aE[j]); e1[j] = f2bf(aE[j + 8]); }
            *(us8*)(xr + 128 + c * 16) = e0;
            *(us8*)(xr + 128 + c * 16 + 8) = e1;
        }
        __syncthreads();   // xe complete

        // ================= tail phase (A-fragments from xe) ================
        // --- node path: h[:,0:256], this wave's 4 chunks ---
        short8 ax[4];
#pragma unroll
        for (int ks = 0; ks < 4; ++ks)
            ax[ks] = *(const short8*)(xe + col16 * 392 + ks * 32 + quad * 8);
#pragma unroll
        for (int ci = 0; ci < 4; ++ci) {
            f32x4 acc = {0.f, 0.f, 0.f, 0.f};
#pragma unroll
            for (int ks = 0; ks < 4; ++ks)
                acc = __builtin_amdgcn_mfma_f32_16x16x32_bf16(ax[ks], bn[ci][ks], acc, 0, 0, 0);
#pragma unroll
            for (int r = 0; r < 4; ++r)
                hw[(quad * 4 + r) * 100 + ci * 16 + col16] =
                    f2bf(fmaxf(acc[r] + bias_n[ci], 0.f));
        }

        // --- edge path: h[:,256:384], this wave's 2 chunks ---
        short8 ae[8];
#pragma unroll
        for (int ks = 0; ks < 8; ++ks)
            ae[ks] = *(const short8*)(xe + col16 * 392 + 128 + ks * 32 + quad * 8);
#pragma unroll
        for (int ci = 0; ci < 2; ++ci) {
            f32x4 acc = {0.f, 0.f, 0.f, 0.f};
#pragma unroll
            for (int ks = 0; ks < 8; ++ks)
                acc = __builtin_amdgcn_mfma_f32_16x16x32_bf16(ae[ks], be[ci][ks], acc, 0, 0, 0);
#pragma unroll
            for (int r = 0; r < 4; ++r)
                hw[(quad * 4 + r) * 100 + 64 + ci * 16 + col16] =
                    f2bf(fmaxf(acc[r] + bias_e[ci], 0.f));
        }

        // --- MLP partial over own 96-K slice (same-wave LDS, no barrier) ---
        f32x4 m0 = {0.f, 0.f, 0.f, 0.f}, m1 = {0.f, 0.f, 0.f, 0.f};
#pragma unroll
        for (int ks = 0; ks < 3; ++ks) {
            short8 a = *(const short8*)(hw + col16 * 100 + ks * 32 + quad * 8);
            m0 = __builtin_amdgcn_mfma_f32_16x16x32_bf16(a, bfr[0][ks], m0, 0, 0, 0);
            m1 = __builtin_amdgcn_mfma_f32_16x16x32_bf16(a, bfr[1][ks], m1, 0, 0, 0);
        }
#pragma unroll
        for (int r = 0; r < 4; ++r) {
            red[wave][quad * 4 + r][col16] = m0[r];
            red[wave][quad * 4 + r][16 + col16] = m1[r];
        }
        __syncthreads();

        // --- final reduce + MLP2 + sigmoid on wave 0 ---
        if (wave == 0) {
            int row = col16, g = quad;          // each lane: 8 cols of one row
            float s = 0.f;
#pragma unroll
            for (int cc = 0; cc < 8; ++cc) {
                int col = g * 8 + cc;
                float v = red[0][row][col] + red[1][row][col] +
                          red[2][row][col] + red[3][row][col] + b_f1[col];
                s += fmaxf(v, 0.f) * W_f2[col];
            }
            s += __shfl_xor(s, 16, 64);
            s += __shfl_xor(s, 32, 64);
            if (g == 0 && r0 + row < N) {
                float v = s + b_f2[0];
                out[r0 + row] = 1.f / (1.f + __expf(-v));
            }
        }
        __syncthreads();   // red + xe reused next tile
    }
}

extern "C" void kernel_launch(void* const* d_in, const int* in_sizes, int n_in,
                              void* d_out, int out_size, void* d_ws, size_t ws_size,
                              hipStream_t stream) {
    const float* x      = (const float*)d_in[0];
    const int*   ei     = (const int*)d_in[1];
    // d_in[2] = e (unused)
    const float* W_node = (const float*)d_in[3];
    const float* b_node = (const float*)d_in[4];
    const float* W_edge = (const float*)d_in[5];
    const float* b_edge = (const float*)d_in[6];
    const float* W_ed   = (const float*)d_in[7];
    const float* b_ed   = (const float*)d_in[8];
    const float* W_f1   = (const float*)d_in[9];
    const float* b_f1   = (const float*)d_in[10];
    const float* W_f2   = (const float*)d_in[11];
    const float* b_f2   = (const float*)d_in[12];

    const int N = in_sizes[0] / 128;
    const int E = in_sizes[1] / 2;
    const int* src = ei;
    const int* dst = ei + E;

    char* ws = (char*)d_ws;
    size_t off = 0;
    auto alloc = [&](size_t bytes) { size_t o = off; off += (bytes + 255) & ~(size_t)255; return o; };
    unsigned short* xb   = (unsigned short*)(ws + alloc((size_t)N * 128 * 2));
    unsigned short* WE2T = (unsigned short*)(ws + alloc(512 * 128 * 2));
    unsigned short* WnT  = (unsigned short*)(ws + alloc(256 * 128 * 2));
    unsigned short* WdT  = (unsigned short*)(ws + alloc(128 * 256 * 2));
    unsigned short* Wf1P = (unsigned short*)(ws + alloc(32 * 384 * 2));
    unsigned short* T    = (unsigned short*)(ws + alloc((size_t)N * 512 * 2));
    int* head            = (int*)(ws + alloc((size_t)N * 4));
    unsigned long long* next2 = (unsigned long long*)(ws + alloc((size_t)E * 8));
    int* deg             = (int*)(ws + alloc((size_t)N * 4));
    int* adj             = (int*)(ws + alloc((size_t)N * 32 * 4));

    const int row_tiles   = (N + 15) / 16;
    const int row_groups  = (row_tiles + 7) / 8;
    const int quads       = N * 128 / 4;
    const int conv_items  = quads + 143360 + N;
    const int scat_blocks = (E + 511) / 512;
    const int gemm_blocks = row_groups;            // wide blocks: 1 per group
    int grid3 = scat_blocks * 3;
    int need_g = ((gemm_blocks + 1) / 2) * 3;
    if (need_g > grid3) grid3 = need_g;

    k_convert<<<(conv_items + 255) / 256, 256, 0, stream>>>(
        x, W_edge, W_node, W_ed, W_f1, xb, WE2T, WnT, WdT, Wf1P, head, deg,
        quads, N);
    k_sg<<<grid3, 512, 0, stream>>>(
        src, dst, head, next2, deg, adj, xb, WE2T, b_edge, T, E, N, row_tiles,
        scat_blocks, gemm_blocks);

    int tail_blocks = 512;
    if (tail_blocks > row_tiles) tail_blocks = row_tiles;
    int tpb = (row_tiles + tail_blocks - 1) / tail_blocks;
    k_tailg<<<tail_blocks, 256, 0, stream>>>(
        T, xb, deg, adj, head, next2, WnT, WdT, Wf1P,
        b_node, b_ed, b_f1, W_f2, b_f2,
        (float*)d_out, N, row_tiles, tpb);
}